// Round 15
// baseline (429.003 us; speedup 1.0000x reference)
//
#include <hip/hip_runtime.h>
#include <hip/hip_bf16.h>

#define N_CELLS  200000
#define N_FACES  400000
#define N_POINTS 200000
#define E_CF     800000
#define E_FP     800000
#define E_PP     1200000
#define CAP_CF   16
#define CAP_FP   24
#define CAP_PP   32
#define OVF_CAP  4096
#define LDA128   136

typedef __attribute__((ext_vector_type(8))) short bf16x8;
typedef __attribute__((ext_vector_type(8))) unsigned short u16x8;
typedef __attribute__((ext_vector_type(4))) float f32x4;

__device__ __forceinline__ float bf2f(unsigned short u) {
    union { unsigned int i; float f; } v; v.i = ((unsigned int)u) << 16; return v.f;
}
__device__ __forceinline__ unsigned short f2bf(float f) {
    __hip_bfloat16 h = __float2bfloat16(f);
    return *reinterpret_cast<unsigned short*>(&h);
}

// ======== fixed-stride fill helper (partitioned sweep) ========
__device__ __forceinline__ void fill_fixed(const int* __restrict__ src,
                                           const int* __restrict__ dst,
                                           const float* __restrict__ ea,
                                           int nE, int rlo, int rhi, int cap,
                                           int tid0, int stride,
                                           int* __restrict__ cnt,
                                           int2* __restrict__ pe,
                                           int* __restrict__ ovfn,
                                           int4* __restrict__ ovf) {
    for (int e = tid0; e < nE; e += stride) {
        int4 d4 = *(const int4*)(dst + e);
        int4 s4 = *(const int4*)(src + e);
        float4 w4 = *(const float4*)(ea + e);
        int dd[4] = {d4.x, d4.y, d4.z, d4.w};
        int ss[4] = {s4.x, s4.y, s4.z, s4.w};
        float ww[4] = {w4.x, w4.y, w4.z, w4.w};
#pragma unroll
        for (int i = 0; i < 4; ++i) {
            int d = dd[i];
            if (d >= rlo && d < rhi) {
                int t = atomicAdd(&cnt[d], 1);
                if (t < cap)
                    pe[(size_t)d * cap + t] = make_int2(ss[i], __float_as_int(ww[i]));
                else {
                    int g = atomicAdd(ovfn, 1);
                    if (g < OVF_CAP) ovf[g] = make_int4(d, ss[i], __float_as_int(ww[i]), 0);
                }
            }
        }
    }
}

// ======== LAUNCH A: fill_cf ∥ fill_fp ∥ pack_fin ∥ Wt precompute ========
__global__ __launch_bounds__(256) void k_fillA(const int* __restrict__ src_cf,
                                               const int* __restrict__ dst_cf,
                                               const float* __restrict__ ea_cf,
                                               int* __restrict__ cnt_cf,
                                               int2* __restrict__ pe_cf,
                                               const int* __restrict__ src_fp,
                                               const int* __restrict__ dst_fp,
                                               const float* __restrict__ ea_fp,
                                               int* __restrict__ cnt_fp,
                                               int2* __restrict__ pe_fp,
                                               int* __restrict__ ovfn,
                                               int4* __restrict__ ovf_cf,
                                               int4* __restrict__ ovf_fp,
                                               const float* __restrict__ W_cf,
                                               const float* __restrict__ b_cf,
                                               const float* __restrict__ W_fp,
                                               const float* __restrict__ b_fp,
                                               const float* __restrict__ W_rt,
                                               const float* __restrict__ W_pp,
                                               float* __restrict__ Wt,
                                               unsigned short* __restrict__ Bp_fin) {
    __shared__ float WcfS[512];
    __shared__ float bcfS[64];
    int b = blockIdx.x;
    if (b < 512) {                                // fill cf (4 partitions x 128 blocks)
        int p = b & 3;
        int blk = b >> 2;
        int rlo = p * 100000, rhi = rlo + 100000;
        int tid0 = (blk * 256 + (int)threadIdx.x) * 4;
        fill_fixed(src_cf, dst_cf, ea_cf, E_CF, rlo, rhi, CAP_CF,
                   tid0, 128 * 256 * 4, cnt_cf, pe_cf, ovfn, ovf_cf);
    } else if (b < 1024) {                        // fill fp
        int bb = b - 512;
        int p = bb & 3;
        int blk = bb >> 2;
        int rlo = p * 50000, rhi = rlo + 50000;
        int tid0 = (blk * 256 + (int)threadIdx.x) * 4;
        fill_fixed(src_fp, dst_fp, ea_fp, E_FP, rlo, rhi, CAP_FP,
                   tid0, 128 * 256 * 4, cnt_fp, pe_fp, ovfn + 1, ovf_fp);
    } else if (b < 1152) {                        // pack fin: 128 blocks
        int t = (b - 1024) * 256 + threadIdx.x;   // 32768
        int j = t & 7, lane = (t >> 3) & 63, ct = (t >> 9) & 7, ks = t >> 12;
        int k = ks * 32 + ((lane >> 4) & 3) * 8 + j;   // 0..255
        int col = ct * 16 + (lane & 15);
        float v = (k < 128) ? W_rt[k * 128 + col] : W_pp[(k - 128) * 128 + col];
        Bp_fin[t] = f2bf(v);
    } else {                                      // Wt precompute (1 block)
        for (int i = threadIdx.x; i < 512; i += 256) WcfS[i] = W_cf[i];
        if (threadIdx.x < 64) bcfS[threadIdx.x] = b_cf[threadIdx.x];
        __syncthreads();
        int t = threadIdx.x;
        int j = t & 127;
        if (t < 128) {                            // rows 0-7 = W_cf@W_fp_top, row16 = b_cf@W_fp_top
            float accW[8] = {};
            float accb = 0.f;
            for (int m = 0; m < 64; ++m) {
                float wf = W_fp[m * 128 + j];
#pragma unroll
                for (int k = 0; k < 8; ++k) accW[k] += WcfS[k * 64 + m] * wf;
                accb += bcfS[m] * wf;
            }
#pragma unroll
            for (int k = 0; k < 8; ++k) Wt[k * 128 + j] = accW[k];
            Wt[16 * 128 + j] = accb;
        } else {                                  // rows 8-15 = W_fp_bot, row17 = b_fp
#pragma unroll
            for (int k = 0; k < 8; ++k) Wt[(8 + k) * 128 + j] = W_fp[(64 + k) * 128 + j];
            Wt[17 * 128 + j] = b_fp[j];
        }
    }
}

// ======== LAUNCH B: fill_pp ∥ aggc-gather (cells->faces, f32 8-col) ========
__global__ __launch_bounds__(256) void k_fillB(const int* __restrict__ src_pp,
                                               const int* __restrict__ dst_pp,
                                               const float* __restrict__ ea_pp,
                                               int* __restrict__ cnt_pp,
                                               int2* __restrict__ pe_pp,
                                               int* __restrict__ ovfn,
                                               int4* __restrict__ ovf_pp,
                                               const float* __restrict__ xc,
                                               const int* __restrict__ cnt_cf,
                                               const int2* __restrict__ pe_cf,
                                               const int* __restrict__ ovfn_cf,
                                               const int4* __restrict__ ovf_cf,
                                               float* __restrict__ aggc) {
    int b = blockIdx.x;
    if (b < 512) {                                // ---- fill pp ----
        int p = b & 3;
        int blk = b >> 2;
        int rlo = p * 50000, rhi = rlo + 50000;
        int tid0 = (blk * 256 + (int)threadIdx.x) * 4;
        fill_fixed(src_pp, dst_pp, ea_pp, E_PP, rlo, rhi, CAP_PP,
                   tid0, 128 * 256 * 4, cnt_pp, pe_pp, ovfn + 2, ovf_pp);
        return;
    }
    // ---- aggc gather: one thread per face row ----
    int r = (b - 512) * 256 + threadIdx.x;
    if (r >= N_FACES) return;
    int n = cnt_cf[r]; if (n > CAP_CF) n = CAP_CF;
    const int2* prow = pe_cf + (size_t)r * CAP_CF;
    float a[8] = {};
    int e = 0;
    for (; e + 1 < n; e += 2) {
        int2 q0 = prow[e], q1 = prow[e + 1];
        float w0 = __int_as_float(q0.y), w1 = __int_as_float(q1.y);
        const float* p0 = xc + (size_t)q0.x * 8;
        const float* p1 = xc + (size_t)q1.x * 8;
        float4 u0 = *(const float4*)p0, u1 = *(const float4*)(p0 + 4);
        float4 v0 = *(const float4*)p1, v1 = *(const float4*)(p1 + 4);
        a[0] += w0 * u0.x + w1 * v0.x; a[1] += w0 * u0.y + w1 * v0.y;
        a[2] += w0 * u0.z + w1 * v0.z; a[3] += w0 * u0.w + w1 * v0.w;
        a[4] += w0 * u1.x + w1 * v1.x; a[5] += w0 * u1.y + w1 * v1.y;
        a[6] += w0 * u1.z + w1 * v1.z; a[7] += w0 * u1.w + w1 * v1.w;
    }
    if (e < n) {
        int2 q0 = prow[e];
        float w0 = __int_as_float(q0.y);
        const float* p0 = xc + (size_t)q0.x * 8;
        float4 u0 = *(const float4*)p0, u1 = *(const float4*)(p0 + 4);
        a[0] += w0 * u0.x; a[1] += w0 * u0.y; a[2] += w0 * u0.z; a[3] += w0 * u0.w;
        a[4] += w0 * u1.x; a[5] += w0 * u1.y; a[6] += w0 * u1.z; a[7] += w0 * u1.w;
    }
    int no = *ovfn_cf;
    if (no > 0) {
        if (no > OVF_CAP) no = OVF_CAP;
        for (int i = 0; i < no; ++i) {
            int4 o = ovf_cf[i];
            if (o.x == r) {
                float w0 = __int_as_float(o.z);
                const float* p0 = xc + (size_t)o.y * 8;
#pragma unroll
                for (int k = 0; k < 8; ++k) a[k] += w0 * p0[k];
            }
        }
    }
    float4* o4 = (float4*)(aggc + (size_t)r * 8);
    o4[0] = make_float4(a[0], a[1], a[2], a[3]);
    o4[1] = make_float4(a[4], a[5], a[6], a[7]);
}

// ======== LAUNCH C: gather {G,X,s} per point + K=17 transform -> y_ptb ========
__global__ __launch_bounds__(256) void k_g17(const float* __restrict__ aggc,
                                             const float* __restrict__ x_face,
                                             const int* __restrict__ cnt,
                                             const int2* __restrict__ pe,
                                             const int* __restrict__ ovfn,
                                             const int4* __restrict__ ovf,
                                             const float* __restrict__ Wt,
                                             unsigned short* __restrict__ y_ptb) {
    __shared__ float A_s[32][18];
    __shared__ float Wt_s[18 * 128];              // 9.2 KB
    for (int i = threadIdx.x; i < 18 * 128; i += 256) Wt_s[i] = Wt[i];
    const int hw = threadIdx.x >> 5;              // 0..7 half-waves
    const int l = threadIdx.x & 31;
    const int R0 = blockIdx.x * 32;
    for (int pp = 0; pp < 4; ++pp) {
        int row = R0 + hw * 4 + pp;
        int n = cnt[row]; if (n > CAP_FP) n = CAP_FP;
        const int2* prow = pe + (size_t)row * CAP_FP;
        float acc = 0.f;
        int e = 0;
        for (; e + 3 < n; e += 4) {
            int2 q0 = prow[e], q1 = prow[e + 1], q2 = prow[e + 2], q3 = prow[e + 3];
#pragma unroll
            for (int k = 0; k < 4; ++k) {
                int2 q = (k == 0) ? q0 : (k == 1) ? q1 : (k == 2) ? q2 : q3;
                float w = __int_as_float(q.y);
                float v;
                if (l < 8)       v = aggc[(size_t)q.x * 8 + l];
                else if (l < 16) v = x_face[(size_t)q.x * 8 + (l - 8)];
                else             v = (l == 16) ? 1.0f : 0.0f;
                acc += w * v;
            }
        }
        for (; e < n; ++e) {
            int2 q = prow[e];
            float w = __int_as_float(q.y);
            float v;
            if (l < 8)       v = aggc[(size_t)q.x * 8 + l];
            else if (l < 16) v = x_face[(size_t)q.x * 8 + (l - 8)];
            else             v = (l == 16) ? 1.0f : 0.0f;
            acc += w * v;
        }
        int no = *ovfn;
        if (no > 0) {
            if (no > OVF_CAP) no = OVF_CAP;
            for (int i = 0; i < no; ++i) {
                int4 o = ovf[i];
                if (o.x == row) {
                    float w = __int_as_float(o.z);
                    float v;
                    if (l < 8)       v = aggc[(size_t)o.y * 8 + l];
                    else if (l < 16) v = x_face[(size_t)o.y * 8 + (l - 8)];
                    else             v = (l == 16) ? 1.0f : 0.0f;
                    acc += w * v;
                }
            }
        }
        if (l < 17) A_s[row - R0][l] = acc;
    }
    __syncthreads();
    // transform: 256 threads, thread = (row r, 16-col chunk jc)
    const int r = threadIdx.x >> 3;
    const int jc = (threadIdx.x & 7) * 16;
    float acc2[16];
#pragma unroll
    for (int i = 0; i < 16; ++i) acc2[i] = Wt_s[17 * 128 + jc + i];   // b_fp
    for (int k = 0; k < 17; ++k) {
        float av = A_s[r][k];
        const float* wr = Wt_s + k * 128 + jc;
#pragma unroll
        for (int i = 0; i < 16; ++i) acc2[i] += av * wr[i];
    }
    u16x8 o0, o1;
#pragma unroll
    for (int i = 0; i < 8; ++i) { o0[i] = f2bf(acc2[i]); o1[i] = f2bf(acc2[8 + i]); }
    unsigned short* orow = y_ptb + (size_t)(R0 + r) * 128 + jc;
    *(u16x8*)orow = o0;
    *(u16x8*)(orow + 8) = o1;
}

// ======== LAUNCH D: gather128pp (32 rows -> LDS) + final MFMA -> out ========
__global__ __launch_bounds__(256) void k_gpp_fin(const unsigned short* __restrict__ feat,
                                                 const int* __restrict__ cnt,
                                                 const int2* __restrict__ pe,
                                                 const int* __restrict__ ovfn,
                                                 const int4* __restrict__ ovf,
                                                 const unsigned short* __restrict__ A1,
                                                 const unsigned short* __restrict__ Bp,
                                                 const float* __restrict__ bias,
                                                 float* __restrict__ out) {
    __shared__ __align__(16) unsigned short Asub[32 * LDA128];
    const int w = threadIdx.x >> 6;
    const int lane = threadIdx.x & 63;
    const int l = lane & 31;
    const int R0 = blockIdx.x * 32;
    for (int rr = 0; rr < 4; ++rr) {
        int row = R0 + w * 8 + rr * 2 + (lane >> 5);
        int n = cnt[row]; if (n > CAP_PP) n = CAP_PP;
        const int2* prow = pe + (size_t)row * CAP_PP;
        float a0 = 0.f, a1 = 0.f, a2 = 0.f, a3 = 0.f;
        int e = 0;
        for (; e + 3 < n; e += 4) {
            int2 q0 = prow[e], q1 = prow[e + 1], q2 = prow[e + 2], q3 = prow[e + 3];
            float w0 = __int_as_float(q0.y), w1 = __int_as_float(q1.y);
            float w2 = __int_as_float(q2.y), w3 = __int_as_float(q3.y);
            const unsigned short* f0 = feat + ((size_t)q0.x << 7) + l;
            const unsigned short* f1 = feat + ((size_t)q1.x << 7) + l;
            const unsigned short* f2 = feat + ((size_t)q2.x << 7) + l;
            const unsigned short* f3 = feat + ((size_t)q3.x << 7) + l;
            a0 += w0 * bf2f(f0[0])  + w1 * bf2f(f1[0])  + w2 * bf2f(f2[0])  + w3 * bf2f(f3[0]);
            a1 += w0 * bf2f(f0[32]) + w1 * bf2f(f1[32]) + w2 * bf2f(f2[32]) + w3 * bf2f(f3[32]);
            a2 += w0 * bf2f(f0[64]) + w1 * bf2f(f1[64]) + w2 * bf2f(f2[64]) + w3 * bf2f(f3[64]);
            a3 += w0 * bf2f(f0[96]) + w1 * bf2f(f1[96]) + w2 * bf2f(f2[96]) + w3 * bf2f(f3[96]);
        }
        for (; e < n; ++e) {
            int2 q0 = prow[e];
            float w0 = __int_as_float(q0.y);
            const unsigned short* f0 = feat + ((size_t)q0.x << 7) + l;
            a0 += w0 * bf2f(f0[0]);  a1 += w0 * bf2f(f0[32]);
            a2 += w0 * bf2f(f0[64]); a3 += w0 * bf2f(f0[96]);
        }
        int no = *ovfn;
        if (no > 0) {
            if (no > OVF_CAP) no = OVF_CAP;
            for (int i = 0; i < no; ++i) {
                int4 o = ovf[i];
                if (o.x == row) {
                    float w0 = __int_as_float(o.z);
                    const unsigned short* f0 = feat + ((size_t)o.y << 7) + l;
                    a0 += w0 * bf2f(f0[0]);  a1 += w0 * bf2f(f0[32]);
                    a2 += w0 * bf2f(f0[64]); a3 += w0 * bf2f(f0[96]);
                }
            }
        }
        int lr = row - R0;
        Asub[lr * LDA128 + l]      = f2bf(a0);
        Asub[lr * LDA128 + 32 + l] = f2bf(a1);
        Asub[lr * LDA128 + 64 + l] = f2bf(a2);
        Asub[lr * LDA128 + 96 + l] = f2bf(a3);
    }
    __syncthreads();
    const int rg = w >> 1, cg = w & 1;
    bf16x8 bfr[8][4];
#pragma unroll
    for (int ks = 0; ks < 8; ++ks)
#pragma unroll
        for (int c = 0; c < 4; ++c) {
            int ct = cg * 4 + c;
            bfr[ks][c] = *(const bf16x8*)(Bp + ((size_t)(ks * 8 + ct) * 64 + lane) * 8);
        }
    f32x4 acc[4] = {};
    const unsigned short* a1p = A1 + (size_t)(R0 + rg * 16 + (lane & 15)) * 128 + ((lane >> 4) * 8);
    const unsigned short* a2p = Asub + (rg * 16 + (lane & 15)) * LDA128 + ((lane >> 4) * 8);
#pragma unroll
    for (int ks = 0; ks < 4; ++ks) {
        bf16x8 af = *(const bf16x8*)(a1p + ks * 32);
#pragma unroll
        for (int c = 0; c < 4; ++c)
            acc[c] = __builtin_amdgcn_mfma_f32_16x16x32_bf16(af, bfr[ks][c], acc[c], 0, 0, 0);
    }
#pragma unroll
    for (int ks = 0; ks < 4; ++ks) {
        bf16x8 af = *(const bf16x8*)(a2p + ks * 32);
#pragma unroll
        for (int c = 0; c < 4; ++c)
            acc[c] = __builtin_amdgcn_mfma_f32_16x16x32_bf16(af, bfr[ks + 4][c], acc[c], 0, 0, 0);
    }
    const int row0 = R0 + rg * 16;
    const int rbase = row0 + (lane >> 4) * 4;
#pragma unroll
    for (int c = 0; c < 4; ++c) {
        int gcol = cg * 64 + c * 16 + (lane & 15);
        float bv = bias[gcol];
#pragma unroll
        for (int r = 0; r < 4; ++r)
            __builtin_nontemporal_store(acc[c][r] + bv,
                                        &out[(size_t)(rbase + r) * 128 + gcol]);
    }
}

extern "C" void kernel_launch(void* const* d_in, const int* in_sizes, int n_in,
                              void* d_out, int out_size, void* d_ws, size_t ws_size,
                              hipStream_t stream) {
    const float* x_centers = (const float*)d_in[0];
    const float* x_face    = (const float*)d_in[1];
    const float* W_cf      = (const float*)d_in[2];
    const float* b_cf      = (const float*)d_in[3];
    const float* W_fp      = (const float*)d_in[4];
    const float* b_fp      = (const float*)d_in[5];
    const float* W_pp      = (const float*)d_in[6];
    const float* W_rt      = (const float*)d_in[7];
    const float* b_pp      = (const float*)d_in[8];
    const float* ea_cf     = (const float*)d_in[9];
    const float* ea_fp     = (const float*)d_in[10];
    const float* ea_pp     = (const float*)d_in[11];
    const int* src_cf      = (const int*)d_in[12];
    const int* dst_cf      = (const int*)d_in[13];
    const int* src_fp      = (const int*)d_in[14];
    const int* dst_fp      = (const int*)d_in[15];
    const int* src_pp      = (const int*)d_in[16];
    const int* dst_pp      = (const int*)d_in[17];
    float* out = (float*)d_out;

    char* ws = (char*)d_ws;
    float* aggc            = (float*)(ws + 0);                    // f32 [400k][8]   12.8MB
    unsigned short* y_ptb  = (unsigned short*)(ws + 16000000);    // bf16 [200k][128] 51.2MB
    float* Wt              = (float*)(ws + 68000000);             // f32 [18][128]   9.2KB
    int2* pe_fp            = (int2*)(ws + 70000000);              // 38.4MB
    int2* pe_cf            = (int2*)(ws + 110000000);             // 51.2MB
    int2* pe_pp            = (int2*)(ws + 162000000);             // 51.2MB
    int*  cnt_cf           = (int*)(ws + 280000000);              // 400k ints
    int*  cnt_fp           = (int*)(ws + 281600000);              // 200k
    int*  cnt_pp           = (int*)(ws + 282400000);              // 200k
    int*  ovfn             = (int*)(ws + 283200000);              // 4 ints (memset-covered)
    int4* ovf_cf           = (int4*)(ws + 284000000);             // 64KB
    int4* ovf_fp           = (int4*)(ws + 284100000);
    int4* ovf_pp           = (int4*)(ws + 284200000);
    unsigned short* Bp_fin = (unsigned short*)(ws + 284400000);   // 64KB

    // zero counters (cnt_cf..ovfn contiguous) in one async memset
    hipMemsetAsync(cnt_cf, 0, 3200016, stream);
    // LAUNCH A: fill_cf ∥ fill_fp ∥ pack_fin ∥ Wt precompute
    k_fillA<<<1153, 256, 0, stream>>>(src_cf, dst_cf, ea_cf, cnt_cf, pe_cf,
                                      src_fp, dst_fp, ea_fp, cnt_fp, pe_fp,
                                      ovfn, ovf_cf, ovf_fp,
                                      W_cf, b_cf, W_fp, b_fp, W_rt, W_pp,
                                      Wt, Bp_fin);
    // LAUNCH B: fill_pp ∥ aggc gather
    k_fillB<<<512 + 1563, 256, 0, stream>>>(src_pp, dst_pp, ea_pp, cnt_pp, pe_pp,
                                            ovfn, ovf_pp,
                                            x_centers, cnt_cf, pe_cf, ovfn, ovf_cf,
                                            aggc);
    // LAUNCH C: {G,X,s} gather + K=17 transform -> y_ptb
    k_g17<<<6250, 256, 0, stream>>>(aggc, x_face, cnt_fp, pe_fp, ovfn + 1, ovf_fp, Wt, y_ptb);
    // LAUNCH D: points->points gather + final MFMA -> out
    k_gpp_fin<<<6250, 256, 0, stream>>>(y_ptb, cnt_pp, pe_pp, ovfn + 2, ovf_pp,
                                        y_ptb, Bp_fin, b_pp, out);
}

// Round 16
// 372.978 us; speedup vs baseline: 1.1502x; 1.1502x over previous
//
#include <hip/hip_runtime.h>
#include <hip/hip_bf16.h>

#define N_CELLS  200000
#define N_FACES  400000
#define N_POINTS 200000
#define E_CF     800000
#define E_FP     800000
#define E_PP     1200000
#define CAP_CF   16
#define CAP_FP   24
#define CAP_PP   32
#define OVF_CAP  4096
#define LDA128   136

typedef __attribute__((ext_vector_type(8))) short bf16x8;
typedef __attribute__((ext_vector_type(8))) unsigned short u16x8;
typedef __attribute__((ext_vector_type(4))) float f32x4;

__device__ __forceinline__ float bf2f(unsigned short u) {
    union { unsigned int i; float f; } v; v.i = ((unsigned int)u) << 16; return v.f;
}
__device__ __forceinline__ unsigned short f2bf(float f) {
    __hip_bfloat16 h = __float2bfloat16(f);
    return *reinterpret_cast<unsigned short*>(&h);
}
__device__ __forceinline__ int2 ldnt2(const int2* p) {
    long long v = __builtin_nontemporal_load((const long long*)p);
    int2 r; r.x = (int)(v & 0xffffffffLL); r.y = (int)(v >> 32); return r;
}

// ======== fixed-stride fill helper (partitioned sweep) ========
__device__ __forceinline__ void fill_fixed(const int* __restrict__ src,
                                           const int* __restrict__ dst,
                                           const float* __restrict__ ea,
                                           int nE, int rlo, int rhi, int cap,
                                           int tid0, int stride,
                                           int* __restrict__ cnt,
                                           int2* __restrict__ pe,
                                           int* __restrict__ ovfn,
                                           int4* __restrict__ ovf) {
    for (int e = tid0; e < nE; e += stride) {
        int4 d4 = *(const int4*)(dst + e);
        int4 s4 = *(const int4*)(src + e);
        float4 w4 = *(const float4*)(ea + e);
        int dd[4] = {d4.x, d4.y, d4.z, d4.w};
        int ss[4] = {s4.x, s4.y, s4.z, s4.w};
        float ww[4] = {w4.x, w4.y, w4.z, w4.w};
#pragma unroll
        for (int i = 0; i < 4; ++i) {
            int d = dd[i];
            if (d >= rlo && d < rhi) {
                int t = atomicAdd(&cnt[d], 1);
                if (t < cap)
                    pe[(size_t)d * cap + t] = make_int2(ss[i], __float_as_int(ww[i]));
                else {
                    int g = atomicAdd(ovfn, 1);
                    if (g < OVF_CAP) ovf[g] = make_int4(d, ss[i], __float_as_int(ww[i]), 0);
                }
            }
        }
    }
}

// ======== LAUNCH A: fill_cf ∥ fill_fp ∥ pack_fin ∥ Wt precompute ========
__global__ __launch_bounds__(256) void k_fillA(const int* __restrict__ src_cf,
                                               const int* __restrict__ dst_cf,
                                               const float* __restrict__ ea_cf,
                                               int* __restrict__ cnt_cf,
                                               int2* __restrict__ pe_cf,
                                               const int* __restrict__ src_fp,
                                               const int* __restrict__ dst_fp,
                                               const float* __restrict__ ea_fp,
                                               int* __restrict__ cnt_fp,
                                               int2* __restrict__ pe_fp,
                                               int* __restrict__ ovfn,
                                               int4* __restrict__ ovf_cf,
                                               int4* __restrict__ ovf_fp,
                                               const float* __restrict__ W_cf,
                                               const float* __restrict__ b_cf,
                                               const float* __restrict__ W_fp,
                                               const float* __restrict__ b_fp,
                                               const float* __restrict__ W_rt,
                                               const float* __restrict__ W_pp,
                                               float* __restrict__ Wt,
                                               unsigned short* __restrict__ Bp_fin) {
    __shared__ float WcfS[512];
    __shared__ float bcfS[64];
    int b = blockIdx.x;
    if (b < 512) {                                // fill cf
        int p = b & 3;
        int blk = b >> 2;
        int rlo = p * 100000, rhi = rlo + 100000;
        int tid0 = (blk * 256 + (int)threadIdx.x) * 4;
        fill_fixed(src_cf, dst_cf, ea_cf, E_CF, rlo, rhi, CAP_CF,
                   tid0, 128 * 256 * 4, cnt_cf, pe_cf, ovfn, ovf_cf);
    } else if (b < 1024) {                        // fill fp
        int bb = b - 512;
        int p = bb & 3;
        int blk = bb >> 2;
        int rlo = p * 50000, rhi = rlo + 50000;
        int tid0 = (blk * 256 + (int)threadIdx.x) * 4;
        fill_fixed(src_fp, dst_fp, ea_fp, E_FP, rlo, rhi, CAP_FP,
                   tid0, 128 * 256 * 4, cnt_fp, pe_fp, ovfn + 1, ovf_fp);
    } else if (b < 1152) {                        // pack fin: 128 blocks
        int t = (b - 1024) * 256 + threadIdx.x;   // 32768
        int j = t & 7, lane = (t >> 3) & 63, ct = (t >> 9) & 7, ks = t >> 12;
        int k = ks * 32 + ((lane >> 4) & 3) * 8 + j;   // 0..255
        int col = ct * 16 + (lane & 15);
        float v = (k < 128) ? W_rt[k * 128 + col] : W_pp[(k - 128) * 128 + col];
        Bp_fin[t] = f2bf(v);
    } else {                                      // Wt precompute (1 block)
        for (int i = threadIdx.x; i < 512; i += 256) WcfS[i] = W_cf[i];
        if (threadIdx.x < 64) bcfS[threadIdx.x] = b_cf[threadIdx.x];
        __syncthreads();
        int t = threadIdx.x;
        int j = t & 127;
        if (t < 128) {                            // rows 0-7 = W_cf@W_fp_top, row16 = b_cf@W_fp_top
            float accW[8] = {};
            float accb = 0.f;
            for (int m = 0; m < 64; ++m) {
                float wf = W_fp[m * 128 + j];
#pragma unroll
                for (int k = 0; k < 8; ++k) accW[k] += WcfS[k * 64 + m] * wf;
                accb += bcfS[m] * wf;
            }
#pragma unroll
            for (int k = 0; k < 8; ++k) Wt[k * 128 + j] = accW[k];
            Wt[16 * 128 + j] = accb;
        } else {                                  // rows 8-15 = W_fp_bot, row17 = b_fp
#pragma unroll
            for (int k = 0; k < 8; ++k) Wt[(8 + k) * 128 + j] = W_fp[(64 + k) * 128 + j];
            Wt[17 * 128 + j] = b_fp[j];
        }
    }
}

// ======== LAUNCH B: fill_pp ∥ aggcx-gather (fused [aggc|x_face] 16-col f32) ========
__global__ __launch_bounds__(256) void k_fillB(const int* __restrict__ src_pp,
                                               const int* __restrict__ dst_pp,
                                               const float* __restrict__ ea_pp,
                                               int* __restrict__ cnt_pp,
                                               int2* __restrict__ pe_pp,
                                               int* __restrict__ ovfn,
                                               int4* __restrict__ ovf_pp,
                                               const float* __restrict__ xc,
                                               const int* __restrict__ cnt_cf,
                                               const int2* __restrict__ pe_cf,
                                               const int* __restrict__ ovfn_cf,
                                               const int4* __restrict__ ovf_cf,
                                               const float* __restrict__ x_face,
                                               float* __restrict__ aggcx) {
    int b = blockIdx.x;
    if (b < 512) {                                // ---- fill pp ----
        int p = b & 3;
        int blk = b >> 2;
        int rlo = p * 50000, rhi = rlo + 50000;
        int tid0 = (blk * 256 + (int)threadIdx.x) * 4;
        fill_fixed(src_pp, dst_pp, ea_pp, E_PP, rlo, rhi, CAP_PP,
                   tid0, 128 * 256 * 4, cnt_pp, pe_pp, ovfn + 2, ovf_pp);
        return;
    }
    // ---- aggcx gather: one thread per face row ----
    int r = (b - 512) * 256 + threadIdx.x;
    if (r >= N_FACES) return;
    int n = cnt_cf[r]; if (n > CAP_CF) n = CAP_CF;
    const int2* prow = pe_cf + (size_t)r * CAP_CF;
    float a[8] = {};
    int e = 0;
    for (; e + 1 < n; e += 2) {
        int2 q0 = prow[e], q1 = prow[e + 1];
        float w0 = __int_as_float(q0.y), w1 = __int_as_float(q1.y);
        const float* p0 = xc + (size_t)q0.x * 8;
        const float* p1 = xc + (size_t)q1.x * 8;
        float4 u0 = *(const float4*)p0, u1 = *(const float4*)(p0 + 4);
        float4 v0 = *(const float4*)p1, v1 = *(const float4*)(p1 + 4);
        a[0] += w0 * u0.x + w1 * v0.x; a[1] += w0 * u0.y + w1 * v0.y;
        a[2] += w0 * u0.z + w1 * v0.z; a[3] += w0 * u0.w + w1 * v0.w;
        a[4] += w0 * u1.x + w1 * v1.x; a[5] += w0 * u1.y + w1 * v1.y;
        a[6] += w0 * u1.z + w1 * v1.z; a[7] += w0 * u1.w + w1 * v1.w;
    }
    if (e < n) {
        int2 q0 = prow[e];
        float w0 = __int_as_float(q0.y);
        const float* p0 = xc + (size_t)q0.x * 8;
        float4 u0 = *(const float4*)p0, u1 = *(const float4*)(p0 + 4);
        a[0] += w0 * u0.x; a[1] += w0 * u0.y; a[2] += w0 * u0.z; a[3] += w0 * u0.w;
        a[4] += w0 * u1.x; a[5] += w0 * u1.y; a[6] += w0 * u1.z; a[7] += w0 * u1.w;
    }
    int no = *ovfn_cf;
    if (no > 0) {
        if (no > OVF_CAP) no = OVF_CAP;
        for (int i = 0; i < no; ++i) {
            int4 o = ovf_cf[i];
            if (o.x == r) {
                float w0 = __int_as_float(o.z);
                const float* p0 = xc + (size_t)o.y * 8;
#pragma unroll
                for (int k = 0; k < 8; ++k) a[k] += w0 * p0[k];
            }
        }
    }
    float4 xf0 = *(const float4*)(x_face + (size_t)r * 8);
    float4 xf1 = *(const float4*)(x_face + (size_t)r * 8 + 4);
    float4* o4 = (float4*)(aggcx + (size_t)r * 16);
    o4[0] = make_float4(a[0], a[1], a[2], a[3]);
    o4[1] = make_float4(a[4], a[5], a[6], a[7]);
    o4[2] = xf0;
    o4[3] = xf1;
}

// ======== LAUNCH C: thread-per-point gather of [G|X],s + K=17 transform -> y_ptb ========
__global__ __launch_bounds__(256) void k_g17(const float* __restrict__ aggcx,
                                             const int* __restrict__ cnt,
                                             const int2* __restrict__ pe,
                                             const int* __restrict__ ovfn,
                                             const int4* __restrict__ ovf,
                                             const float* __restrict__ Wt,
                                             unsigned short* __restrict__ y_ptb) {
    int row = blockIdx.x * 256 + threadIdx.x;
    if (row >= N_POINTS) return;
    int n = cnt[row]; if (n > CAP_FP) n = CAP_FP;
    const int2* prow = pe + (size_t)row * CAP_FP;
    float a[16] = {};
    float s = 0.f;
    int e = 0;
    for (; e + 1 < n; e += 2) {
        int2 q0 = ldnt2(prow + e);
        int2 q1 = ldnt2(prow + e + 1);
        float w0 = __int_as_float(q0.y), w1 = __int_as_float(q1.y);
        const float4* v0 = (const float4*)(aggcx + (size_t)q0.x * 16);
        const float4* v1 = (const float4*)(aggcx + (size_t)q1.x * 16);
#pragma unroll
        for (int j = 0; j < 4; ++j) {
            float4 u = v0[j], v = v1[j];
            a[4 * j + 0] += w0 * u.x + w1 * v.x;
            a[4 * j + 1] += w0 * u.y + w1 * v.y;
            a[4 * j + 2] += w0 * u.z + w1 * v.z;
            a[4 * j + 3] += w0 * u.w + w1 * v.w;
        }
        s += w0 + w1;
    }
    if (e < n) {
        int2 q0 = ldnt2(prow + e);
        float w0 = __int_as_float(q0.y);
        const float4* v0 = (const float4*)(aggcx + (size_t)q0.x * 16);
#pragma unroll
        for (int j = 0; j < 4; ++j) {
            float4 u = v0[j];
            a[4 * j + 0] += w0 * u.x; a[4 * j + 1] += w0 * u.y;
            a[4 * j + 2] += w0 * u.z; a[4 * j + 3] += w0 * u.w;
        }
        s += w0;
    }
    int no = *ovfn;
    if (no > 0) {
        if (no > OVF_CAP) no = OVF_CAP;
        for (int i = 0; i < no; ++i) {
            int4 o = ovf[i];
            if (o.x == row) {
                float w0 = __int_as_float(o.z);
                const float* v0 = aggcx + (size_t)o.y * 16;
#pragma unroll
                for (int k = 0; k < 16; ++k) a[k] += w0 * v0[k];
                s += w0;
            }
        }
    }
    // transform: y[j] = b_fp[j] + sum_k a[k]*Wt[k][j] + s*Wt[16][j]  (Wt reads are lane-uniform)
    unsigned short* orow = y_ptb + (size_t)row * 128;
    for (int jc = 0; jc < 128; jc += 16) {
        float acc2[16];
        const float4* bb = (const float4*)(Wt + 17 * 128 + jc);
#pragma unroll
        for (int j4 = 0; j4 < 4; ++j4) {
            float4 w4 = bb[j4];
            acc2[4 * j4 + 0] = w4.x; acc2[4 * j4 + 1] = w4.y;
            acc2[4 * j4 + 2] = w4.z; acc2[4 * j4 + 3] = w4.w;
        }
#pragma unroll
        for (int k = 0; k < 16; ++k) {
            float av = a[k];
            const float4* wr = (const float4*)(Wt + k * 128 + jc);
#pragma unroll
            for (int j4 = 0; j4 < 4; ++j4) {
                float4 w4 = wr[j4];
                acc2[4 * j4 + 0] += av * w4.x; acc2[4 * j4 + 1] += av * w4.y;
                acc2[4 * j4 + 2] += av * w4.z; acc2[4 * j4 + 3] += av * w4.w;
            }
        }
        {
            const float4* wr = (const float4*)(Wt + 16 * 128 + jc);
#pragma unroll
            for (int j4 = 0; j4 < 4; ++j4) {
                float4 w4 = wr[j4];
                acc2[4 * j4 + 0] += s * w4.x; acc2[4 * j4 + 1] += s * w4.y;
                acc2[4 * j4 + 2] += s * w4.z; acc2[4 * j4 + 3] += s * w4.w;
            }
        }
        u16x8 o0, o1;
#pragma unroll
        for (int i = 0; i < 8; ++i) { o0[i] = f2bf(acc2[i]); o1[i] = f2bf(acc2[8 + i]); }
        *(u16x8*)(orow + jc) = o0;
        *(u16x8*)(orow + jc + 8) = o1;
    }
}

// ======== LAUNCH D: gather128pp (32 rows -> LDS) + final MFMA -> out ========
__global__ __launch_bounds__(256) void k_gpp_fin(const unsigned short* __restrict__ feat,
                                                 const int* __restrict__ cnt,
                                                 const int2* __restrict__ pe,
                                                 const int* __restrict__ ovfn,
                                                 const int4* __restrict__ ovf,
                                                 const unsigned short* __restrict__ A1,
                                                 const unsigned short* __restrict__ Bp,
                                                 const float* __restrict__ bias,
                                                 float* __restrict__ out) {
    __shared__ __align__(16) unsigned short Asub[32 * LDA128];
    const int w = threadIdx.x >> 6;
    const int lane = threadIdx.x & 63;
    const int l = lane & 31;
    const int R0 = blockIdx.x * 32;
    for (int rr = 0; rr < 4; ++rr) {
        int row = R0 + w * 8 + rr * 2 + (lane >> 5);
        int n = cnt[row]; if (n > CAP_PP) n = CAP_PP;
        const int2* prow = pe + (size_t)row * CAP_PP;
        float a0 = 0.f, a1 = 0.f, a2 = 0.f, a3 = 0.f;
        int e = 0;
        for (; e + 3 < n; e += 4) {
            int2 q0 = ldnt2(prow + e),     q1 = ldnt2(prow + e + 1);
            int2 q2 = ldnt2(prow + e + 2), q3 = ldnt2(prow + e + 3);
            float w0 = __int_as_float(q0.y), w1 = __int_as_float(q1.y);
            float w2 = __int_as_float(q2.y), w3 = __int_as_float(q3.y);
            const unsigned short* f0 = feat + ((size_t)q0.x << 7) + l;
            const unsigned short* f1 = feat + ((size_t)q1.x << 7) + l;
            const unsigned short* f2 = feat + ((size_t)q2.x << 7) + l;
            const unsigned short* f3 = feat + ((size_t)q3.x << 7) + l;
            a0 += w0 * bf2f(f0[0])  + w1 * bf2f(f1[0])  + w2 * bf2f(f2[0])  + w3 * bf2f(f3[0]);
            a1 += w0 * bf2f(f0[32]) + w1 * bf2f(f1[32]) + w2 * bf2f(f2[32]) + w3 * bf2f(f3[32]);
            a2 += w0 * bf2f(f0[64]) + w1 * bf2f(f1[64]) + w2 * bf2f(f2[64]) + w3 * bf2f(f3[64]);
            a3 += w0 * bf2f(f0[96]) + w1 * bf2f(f1[96]) + w2 * bf2f(f2[96]) + w3 * bf2f(f3[96]);
        }
        for (; e < n; ++e) {
            int2 q0 = ldnt2(prow + e);
            float w0 = __int_as_float(q0.y);
            const unsigned short* f0 = feat + ((size_t)q0.x << 7) + l;
            a0 += w0 * bf2f(f0[0]);  a1 += w0 * bf2f(f0[32]);
            a2 += w0 * bf2f(f0[64]); a3 += w0 * bf2f(f0[96]);
        }
        int no = *ovfn;
        if (no > 0) {
            if (no > OVF_CAP) no = OVF_CAP;
            for (int i = 0; i < no; ++i) {
                int4 o = ovf[i];
                if (o.x == row) {
                    float w0 = __int_as_float(o.z);
                    const unsigned short* f0 = feat + ((size_t)o.y << 7) + l;
                    a0 += w0 * bf2f(f0[0]);  a1 += w0 * bf2f(f0[32]);
                    a2 += w0 * bf2f(f0[64]); a3 += w0 * bf2f(f0[96]);
                }
            }
        }
        int lr = row - R0;
        Asub[lr * LDA128 + l]      = f2bf(a0);
        Asub[lr * LDA128 + 32 + l] = f2bf(a1);
        Asub[lr * LDA128 + 64 + l] = f2bf(a2);
        Asub[lr * LDA128 + 96 + l] = f2bf(a3);
    }
    __syncthreads();
    const int rg = w >> 1, cg = w & 1;
    bf16x8 bfr[8][4];
#pragma unroll
    for (int ks = 0; ks < 8; ++ks)
#pragma unroll
        for (int c = 0; c < 4; ++c) {
            int ct = cg * 4 + c;
            bfr[ks][c] = *(const bf16x8*)(Bp + ((size_t)(ks * 8 + ct) * 64 + lane) * 8);
        }
    f32x4 acc[4] = {};
    const unsigned short* a1p = A1 + (size_t)(R0 + rg * 16 + (lane & 15)) * 128 + ((lane >> 4) * 8);
    const unsigned short* a2p = Asub + (rg * 16 + (lane & 15)) * LDA128 + ((lane >> 4) * 8);
#pragma unroll
    for (int ks = 0; ks < 4; ++ks) {
        bf16x8 af = *(const bf16x8*)(a1p + ks * 32);
#pragma unroll
        for (int c = 0; c < 4; ++c)
            acc[c] = __builtin_amdgcn_mfma_f32_16x16x32_bf16(af, bfr[ks][c], acc[c], 0, 0, 0);
    }
#pragma unroll
    for (int ks = 0; ks < 4; ++ks) {
        bf16x8 af = *(const bf16x8*)(a2p + ks * 32);
#pragma unroll
        for (int c = 0; c < 4; ++c)
            acc[c] = __builtin_amdgcn_mfma_f32_16x16x32_bf16(af, bfr[ks + 4][c], acc[c], 0, 0, 0);
    }
    const int row0 = R0 + rg * 16;
    const int rbase = row0 + (lane >> 4) * 4;
#pragma unroll
    for (int c = 0; c < 4; ++c) {
        int gcol = cg * 64 + c * 16 + (lane & 15);
        float bv = bias[gcol];
#pragma unroll
        for (int r = 0; r < 4; ++r)
            __builtin_nontemporal_store(acc[c][r] + bv,
                                        &out[(size_t)(rbase + r) * 128 + gcol]);
    }
}

extern "C" void kernel_launch(void* const* d_in, const int* in_sizes, int n_in,
                              void* d_out, int out_size, void* d_ws, size_t ws_size,
                              hipStream_t stream) {
    const float* x_centers = (const float*)d_in[0];
    const float* x_face    = (const float*)d_in[1];
    const float* W_cf      = (const float*)d_in[2];
    const float* b_cf      = (const float*)d_in[3];
    const float* W_fp      = (const float*)d_in[4];
    const float* b_fp      = (const float*)d_in[5];
    const float* W_pp      = (const float*)d_in[6];
    const float* W_rt      = (const float*)d_in[7];
    const float* b_pp      = (const float*)d_in[8];
    const float* ea_cf     = (const float*)d_in[9];
    const float* ea_fp     = (const float*)d_in[10];
    const float* ea_pp     = (const float*)d_in[11];
    const int* src_cf      = (const int*)d_in[12];
    const int* dst_cf      = (const int*)d_in[13];
    const int* src_fp      = (const int*)d_in[14];
    const int* dst_fp      = (const int*)d_in[15];
    const int* src_pp      = (const int*)d_in[16];
    const int* dst_pp      = (const int*)d_in[17];
    float* out = (float*)d_out;

    char* ws = (char*)d_ws;
    float* aggcx           = (float*)(ws + 0);                    // f32 [400k][16]  25.6MB
    unsigned short* y_ptb  = (unsigned short*)(ws + 28000000);    // bf16 [200k][128] 51.2MB
    float* Wt              = (float*)(ws + 80000000);             // f32 [18][128]
    int2* pe_fp            = (int2*)(ws + 81000000);              // 38.4MB
    int2* pe_cf            = (int2*)(ws + 120000000);             // 51.2MB
    int2* pe_pp            = (int2*)(ws + 172000000);             // 51.2MB
    int*  cnt_cf           = (int*)(ws + 280000000);              // 400k ints
    int*  cnt_fp           = (int*)(ws + 281600000);              // 200k
    int*  cnt_pp           = (int*)(ws + 282400000);              // 200k
    int*  ovfn             = (int*)(ws + 283200000);              // 4 ints (memset-covered)
    int4* ovf_cf           = (int4*)(ws + 284000000);             // 64KB
    int4* ovf_fp           = (int4*)(ws + 284100000);
    int4* ovf_pp           = (int4*)(ws + 284200000);
    unsigned short* Bp_fin = (unsigned short*)(ws + 284400000);   // 64KB

    // zero counters (cnt_cf..ovfn contiguous) in one async memset
    hipMemsetAsync(cnt_cf, 0, 3200016, stream);
    // LAUNCH A: fill_cf ∥ fill_fp ∥ pack_fin ∥ Wt precompute
    k_fillA<<<1153, 256, 0, stream>>>(src_cf, dst_cf, ea_cf, cnt_cf, pe_cf,
                                      src_fp, dst_fp, ea_fp, cnt_fp, pe_fp,
                                      ovfn, ovf_cf, ovf_fp,
                                      W_cf, b_cf, W_fp, b_fp, W_rt, W_pp,
                                      Wt, Bp_fin);
    // LAUNCH B: fill_pp ∥ aggcx gather
    k_fillB<<<512 + 1563, 256, 0, stream>>>(src_pp, dst_pp, ea_pp, cnt_pp, pe_pp,
                                            ovfn, ovf_pp,
                                            x_centers, cnt_cf, pe_cf, ovfn, ovf_cf,
                                            x_face, aggcx);
    // LAUNCH C: thread-per-point gather + K=17 transform -> y_ptb
    k_g17<<<782, 256, 0, stream>>>(aggcx, cnt_fp, pe_fp, ovfn + 1, ovf_fp, Wt, y_ptb);
    // LAUNCH D: points->points gather + final MFMA -> out
    k_gpp_fin<<<6250, 256, 0, stream>>>(y_ptb, cnt_pp, pe_pp, ovfn + 2, ovf_pp,
                                        y_ptb, Bp_fin, b_pp, out);
}